// Round 6
// baseline (789.217 us; speedup 1.0000x reference)
//
#include <hip/hip_runtime.h>
#include <hip/hip_bf16.h>

// Problem constants
#define B_   2
#define H_   16
#define SQ_  2048
#define SK_  2048
#define D_   128

// Tiling
#define QT   128
#define KT   32
#define NITER (SK_/KT)   // 64

using bf16x8 = __attribute__((ext_vector_type(8))) __bf16;
using bf16x4 = __attribute__((ext_vector_type(4))) __bf16;
using bf16x2 = __attribute__((ext_vector_type(2))) __bf16;
using f32x4  = __attribute__((ext_vector_type(4))) float;

#define MFMA16(a,b,c) __builtin_amdgcn_mfma_f32_16x16x32_bf16(a,b,c,0,0,0)

// LDS pitches (bf16 elems)
#define K_PITCH  136   // K tile rows 272 B (conflict-free b128 frag reads)
#define VT_PITCH 40    // V^T rows 80 B, XOR chunk swizzle

#define KB_   (KT*K_PITCH*2)      // 8704
#define VTB_  (D_*VT_PITCH*2)     // 10240
#define SMEM_BYTES (2*KB_ + 2*VTB_)   // 37888

__global__ __launch_bounds__(512, 4)
void attn_drop_kernel(const float* __restrict__ Q,
                      const float* __restrict__ K,
                      const float* __restrict__ V,
                      const int*   __restrict__ M,
                      float* __restrict__ Out)
{
    __shared__ __align__(16) char smem[SMEM_BYTES];

    const int tid  = threadIdx.x;
    const int wave = tid >> 6;
    const int lane = tid & 63;
    const int quad = lane >> 4;
    const int ln   = lane & 15;

    // XCD-aware bijective swizzle (512 % 8 == 0): 4 whole heads per XCD
    const int orig = ((blockIdx.x & 7) << 6) | (blockIdx.x >> 3);
    const int bh = orig >> 4;
    const int qb = orig & 15;

    const float* qptr = Q + ((size_t)bh*SQ_ + (size_t)qb*QT) * D_;
    const float* kptr = K + (size_t)bh*SK_*D_;
    const float* vptr = V + (size_t)bh*SK_*D_;
    const int*   mptr = M + (size_t)bh*(size_t)SQ_*SK_ + (size_t)qb*QT*SK_;
    float*       optr = Out + ((size_t)bh*SQ_ + (size_t)qb*QT) * D_;

    const int c  = tid & 31;
    const int g  = tid >> 5;

    // V^T write swizzle: elem offset within a d-row for k-pair {2g,2g+1}
    const int wxor = (2*g) ^ ((c & 3) * 8);

    // Mask: each lane loads exactly what it consumes (S^T layout: q=ln, k=4quad+r)
    const int* mlane = mptr + (size_t)(16*wave + ln)*SK_ + 4*quad;

    // V-read offsets (swizzle-aware)
    const int x3  = (ln >> 2) & 3;
    const int p0c = (quad >> 1) ^ x3;
    const int vlo = 8*p0c       + 4*(quad & 1);
    const int vhi = 8*(p0c ^ 2) + 4*(quad & 1);

    // -------- prefetch registers --------
    float4 kpre0, kpre1, vpre0, vpre1;

    auto load_kv = [&](int kt) {
        const float4* ks = (const float4*)(kptr + (size_t)kt*KT*D_);
        const float4* vs = (const float4*)(vptr + (size_t)kt*KT*D_);
        kpre0 = ks[g*32 + c];
        kpre1 = ks[(g+16)*32 + c];
        vpre0 = vs[(2*g  )*32 + c];
        vpre1 = vs[(2*g+1)*32 + c];
    };

    auto write_tile = [&](int b) {
        __bf16* ksb = (__bf16*)(smem + b*KB_);
        __bf16* vtb = (__bf16*)(smem + 2*KB_ + b*VTB_);
        {
            bf16x4 h0 = { (__bf16)kpre0.x, (__bf16)kpre0.y, (__bf16)kpre0.z, (__bf16)kpre0.w };
            bf16x4 h1 = { (__bf16)kpre1.x, (__bf16)kpre1.y, (__bf16)kpre1.z, (__bf16)kpre1.w };
            *(bf16x4*)&ksb[ g    *K_PITCH + 4*c] = h0;
            *(bf16x4*)&ksb[(g+16)*K_PITCH + 4*c] = h1;
        }
        {
            const float* f0 = (const float*)&vpre0;
            const float* f1 = (const float*)&vpre1;
            #pragma unroll
            for (int j = 0; j < 4; ++j) {
                bf16x2 pr = { (__bf16)f0[j], (__bf16)f1[j] };
                *(bf16x2*)&vtb[(4*c + j)*VT_PITCH + wxor] = pr;
            }
        }
    };

    // prologue: tile 0 in flight; Q fragments straight from global
    load_kv(0);
    int4 mA0 = *(const int4*)(mlane);
    int4 mA1 = *(const int4*)(mlane + 16);
    int4 mB0, mB1;

    bf16x8 qf[4];
    {
        const float* qrow = qptr + (size_t)(16*wave + ln)*D_;
        #pragma unroll
        for (int s = 0; s < 4; ++s) {
            float4 a  = *(const float4*)(qrow + 32*s + 8*quad);
            float4 b2 = *(const float4*)(qrow + 32*s + 8*quad + 4);
            qf[s] = (bf16x8){ (__bf16)a.x,  (__bf16)a.y,  (__bf16)a.z,  (__bf16)a.w,
                              (__bf16)b2.x, (__bf16)b2.y, (__bf16)b2.z, (__bf16)b2.w };
        }
    }

    f32x4 Oacc[8];
    #pragma unroll
    for (int dt = 0; dt < 8; ++dt)
        Oacc[dt] = (f32x4){0.f, 0.f, 0.f, 0.f};

    const int row0 = 16*wave + 4*quad;

// One pipeline step. b, mc*, mn* are textually static (rule #20: no runtime reg-array idx).
// Raw s_barrier + lgkmcnt-only fence: global loads stay in flight across the barrier (T4).
#define STEP(KTI, BSEL, mc0, mc1, mn0, mn1)                                          \
    {                                                                                \
        write_tile(BSEL);           /* vmcnt wait lands here, one full iter of slack */\
        asm volatile("s_waitcnt lgkmcnt(0)" ::: "memory");                           \
        __builtin_amdgcn_s_barrier();                                                \
        if ((KTI) + 1 < NITER) {                                                     \
            load_kv((KTI) + 1);                                                      \
            mn0 = *(const int4*)(mlane + ((KTI)+1)*KT);                              \
            mn1 = *(const int4*)(mlane + ((KTI)+1)*KT + 16);                         \
        }                                                                            \
        const __bf16* ksb = (const __bf16*)(smem + (BSEL)*KB_);                      \
        const __bf16* vtb = (const __bf16*)(smem + 2*KB_ + (BSEL)*VTB_);             \
        f32x4 S0 = (f32x4){0.f,0.f,0.f,0.f};                                         \
        f32x4 S1 = (f32x4){0.f,0.f,0.f,0.f};                                         \
        __builtin_amdgcn_s_setprio(1);                                               \
        _Pragma("unroll")                                                            \
        for (int s = 0; s < 4; ++s) {                                                \
            bf16x8 kf0 = *(const bf16x8*)&ksb[ ln    *K_PITCH + 32*s + 8*quad];      \
            bf16x8 kf1 = *(const bf16x8*)&ksb[(16+ln)*K_PITCH + 32*s + 8*quad];      \
            S0 = MFMA16(kf0, qf[s], S0);                                             \
            S1 = MFMA16(kf1, qf[s], S1);                                             \
        }                                                                            \
        __builtin_amdgcn_s_setprio(0);                                               \
        bf16x8 pa;                                                                   \
        pa[0] = mc0.x ? (__bf16)S0[0] : (__bf16)0.0f;                                \
        pa[1] = mc0.y ? (__bf16)S0[1] : (__bf16)0.0f;                                \
        pa[2] = mc0.z ? (__bf16)S0[2] : (__bf16)0.0f;                                \
        pa[3] = mc0.w ? (__bf16)S0[3] : (__bf16)0.0f;                                \
        pa[4] = mc1.x ? (__bf16)S1[0] : (__bf16)0.0f;                                \
        pa[5] = mc1.y ? (__bf16)S1[1] : (__bf16)0.0f;                                \
        pa[6] = mc1.z ? (__bf16)S1[2] : (__bf16)0.0f;                                \
        pa[7] = mc1.w ? (__bf16)S1[3] : (__bf16)0.0f;                                \
        __builtin_amdgcn_s_setprio(1);                                               \
        _Pragma("unroll")                                                            \
        for (int dt = 0; dt < 8; ++dt) {                                             \
            const __bf16* vrow = &vtb[(16*dt + ln)*VT_PITCH];                        \
            bf16x4 va = *(const bf16x4*)&vrow[vlo];                                  \
            bf16x4 vb = *(const bf16x4*)&vrow[vhi];                                  \
            bf16x8 vf = { va[0], va[1], va[2], va[3], vb[0], vb[1], vb[2], vb[3] };  \
            Oacc[dt] = MFMA16(pa, vf, Oacc[dt]);                                     \
        }                                                                            \
        __builtin_amdgcn_s_setprio(0);                                               \
    }

    for (int kt = 0; kt < NITER; kt += 2) {
        STEP(kt,     0, mA0, mA1, mB0, mB1);
        STEP(kt + 1, 1, mB0, mB1, mA0, mA1);
    }
#undef STEP

    // ---- epilogue: folded scale 2*sqrt(D), store fp32
    const float SCALE = 22.62741699796952f;  // 2 * sqrt(128)
    #pragma unroll
    for (int dt = 0; dt < 8; ++dt) {
        #pragma unroll
        for (int r = 0; r < 4; ++r)
            optr[(size_t)(row0 + r)*D_ + 16*dt + ln] = Oacc[dt][r] * SCALE;
    }
}

extern "C" void kernel_launch(void* const* d_in, const int* in_sizes, int n_in,
                              void* d_out, int out_size, void* d_ws, size_t ws_size,
                              hipStream_t stream) {
    (void)in_sizes; (void)n_in; (void)d_ws; (void)ws_size; (void)out_size;
    const float* Q = (const float*)d_in[0];
    const float* K = (const float*)d_in[1];
    const float* V = (const float*)d_in[2];
    const int*   M = (const int*)d_in[3];
    float* Out = (float*)d_out;

    dim3 grid(B_ * H_ * (SQ_ / QT));   // 512 blocks
    attn_drop_kernel<<<grid, 512, 0, stream>>>(Q, K, V, M, Out);
}

// Round 7
// 781.813 us; speedup vs baseline: 1.0095x; 1.0095x over previous
//
#include <hip/hip_runtime.h>
#include <hip/hip_bf16.h>

// Problem constants
#define B_   2
#define H_   16
#define SQ_  2048
#define SK_  2048
#define D_   128

// Tiling
#define QT   128
#define KT   32
#define NITER (SK_/KT)   // 64

using bf16x8 = __attribute__((ext_vector_type(8))) __bf16;
using bf16x4 = __attribute__((ext_vector_type(4))) __bf16;
using bf16x2 = __attribute__((ext_vector_type(2))) __bf16;
using f32x4  = __attribute__((ext_vector_type(4))) float;

#define MFMA16(a,b,c) __builtin_amdgcn_mfma_f32_16x16x32_bf16(a,b,c,0,0,0)

// LDS pitches (bf16 elems)
#define K_PITCH  136   // K tile rows 272 B (conflict-free b128 frag reads)
#define VT_PITCH 40    // V^T rows 80 B, XOR chunk swizzle

#define KB_   (KT*K_PITCH*2)      // 8704
#define VTB_  (D_*VT_PITCH*2)     // 10240
#define SMEM_BYTES (2*KB_ + 2*VTB_)   // 37888

__global__ __launch_bounds__(512, 4)
void attn_drop_kernel(const float* __restrict__ Q,
                      const float* __restrict__ K,
                      const float* __restrict__ V,
                      const int*   __restrict__ M,
                      float* __restrict__ Out)
{
    __shared__ __align__(16) char smem[SMEM_BYTES];

    const int tid  = threadIdx.x;
    const int wave = tid >> 6;
    const int lane = tid & 63;
    const int quad = lane >> 4;
    const int ln   = lane & 15;

    // XCD-aware bijective swizzle (512 % 8 == 0): 4 whole heads per XCD
    const int orig = ((blockIdx.x & 7) << 6) | (blockIdx.x >> 3);
    const int bh = orig >> 4;
    const int qb = orig & 15;

    // k-loop stagger: all blocks of a head share kt0 (preserves K/V L2 sharing),
    // different heads start at different columns -> HBM channel spread + burst de-phasing.
    // Valid: O = sum over kt of P*V, order-independent (no softmax).
    const int kt0 = (bh * 5) & (NITER - 1);

    const float* qptr = Q + ((size_t)bh*SQ_ + (size_t)qb*QT) * D_;
    const float* kptr = K + (size_t)bh*SK_*D_;
    const float* vptr = V + (size_t)bh*SK_*D_;
    const int*   mptr = M + (size_t)bh*(size_t)SQ_*SK_ + (size_t)qb*QT*SK_;
    float*       optr = Out + ((size_t)bh*SQ_ + (size_t)qb*QT) * D_;

    const int c  = tid & 31;
    const int g  = tid >> 5;

    // V^T write swizzle: elem offset within a d-row for k-pair {2g,2g+1}
    const int wxor = (2*g) ^ ((c & 3) * 8);

    // Mask: each lane loads exactly what it consumes (S^T layout: q=ln, k=4quad+r)
    const int* mlane = mptr + (size_t)(16*wave + ln)*SK_ + 4*quad;

    // V-read offsets (swizzle-aware)
    const int x3  = (ln >> 2) & 3;
    const int p0c = (quad >> 1) ^ x3;
    const int vlo = 8*p0c       + 4*(quad & 1);
    const int vhi = 8*(p0c ^ 2) + 4*(quad & 1);

    // -------- prefetch registers --------
    float4 kpre0, kpre1, vpre0, vpre1;

    auto load_kv = [&](int kt) {   // kt = PHYSICAL tile index
        const float4* ks = (const float4*)(kptr + (size_t)kt*KT*D_);
        const float4* vs = (const float4*)(vptr + (size_t)kt*KT*D_);
        kpre0 = ks[g*32 + c];
        kpre1 = ks[(g+16)*32 + c];
        vpre0 = vs[(2*g  )*32 + c];
        vpre1 = vs[(2*g+1)*32 + c];
    };

    auto write_tile = [&](int b) {
        __bf16* ksb = (__bf16*)(smem + b*KB_);
        __bf16* vtb = (__bf16*)(smem + 2*KB_ + b*VTB_);
        {
            bf16x4 h0 = { (__bf16)kpre0.x, (__bf16)kpre0.y, (__bf16)kpre0.z, (__bf16)kpre0.w };
            bf16x4 h1 = { (__bf16)kpre1.x, (__bf16)kpre1.y, (__bf16)kpre1.z, (__bf16)kpre1.w };
            *(bf16x4*)&ksb[ g    *K_PITCH + 4*c] = h0;
            *(bf16x4*)&ksb[(g+16)*K_PITCH + 4*c] = h1;
        }
        {
            const float* f0 = (const float*)&vpre0;
            const float* f1 = (const float*)&vpre1;
            #pragma unroll
            for (int j = 0; j < 4; ++j) {
                bf16x2 pr = { (__bf16)f0[j], (__bf16)f1[j] };
                *(bf16x2*)&vtb[(4*c + j)*VT_PITCH + wxor] = pr;
            }
        }
    };

    // prologue: tile kt0 in flight; Q fragments straight from global
    load_kv(kt0);
    int4 mA0 = *(const int4*)(mlane + kt0*KT);
    int4 mA1 = *(const int4*)(mlane + kt0*KT + 16);
    int4 mB0, mB1;

    bf16x8 qf[4];
    {
        const float* qrow = qptr + (size_t)(16*wave + ln)*D_;
        #pragma unroll
        for (int s = 0; s < 4; ++s) {
            float4 a  = *(const float4*)(qrow + 32*s + 8*quad);
            float4 b2 = *(const float4*)(qrow + 32*s + 8*quad + 4);
            qf[s] = (bf16x8){ (__bf16)a.x,  (__bf16)a.y,  (__bf16)a.z,  (__bf16)a.w,
                              (__bf16)b2.x, (__bf16)b2.y, (__bf16)b2.z, (__bf16)b2.w };
        }
    }

    f32x4 Oacc[8];
    #pragma unroll
    for (int dt = 0; dt < 8; ++dt)
        Oacc[dt] = (f32x4){0.f, 0.f, 0.f, 0.f};

    const int row0 = 16*wave + 4*quad;

// One pipeline step over LOGICAL iteration ITI; physical tile = (ITI + kt0) & 63.
// Raw s_barrier + lgkmcnt-only fence: global loads stay in flight across the barrier.
#define STEP(ITI, BSEL, mc0, mc1, mn0, mn1)                                          \
    {                                                                                \
        write_tile(BSEL);                                                            \
        asm volatile("s_waitcnt lgkmcnt(0)" ::: "memory");                           \
        __builtin_amdgcn_s_barrier();                                                \
        if ((ITI) + 1 < NITER) {                                                     \
            const int ktn = ((ITI) + 1 + kt0) & (NITER - 1);                         \
            load_kv(ktn);                                                            \
            mn0 = *(const int4*)(mlane + ktn*KT);                                    \
            mn1 = *(const int4*)(mlane + ktn*KT + 16);                               \
        }                                                                            \
        const __bf16* ksb = (const __bf16*)(smem + (BSEL)*KB_);                      \
        const __bf16* vtb = (const __bf16*)(smem + 2*KB_ + (BSEL)*VTB_);             \
        f32x4 S0 = (f32x4){0.f,0.f,0.f,0.f};                                         \
        f32x4 S1 = (f32x4){0.f,0.f,0.f,0.f};                                         \
        __builtin_amdgcn_s_setprio(1);                                               \
        _Pragma("unroll")                                                            \
        for (int s = 0; s < 4; ++s) {                                                \
            bf16x8 kf0 = *(const bf16x8*)&ksb[ ln    *K_PITCH + 32*s + 8*quad];      \
            bf16x8 kf1 = *(const bf16x8*)&ksb[(16+ln)*K_PITCH + 32*s + 8*quad];      \
            S0 = MFMA16(kf0, qf[s], S0);                                             \
            S1 = MFMA16(kf1, qf[s], S1);                                             \
        }                                                                            \
        __builtin_amdgcn_s_setprio(0);                                               \
        bf16x8 pa;                                                                   \
        pa[0] = mc0.x ? (__bf16)S0[0] : (__bf16)0.0f;                                \
        pa[1] = mc0.y ? (__bf16)S0[1] : (__bf16)0.0f;                                \
        pa[2] = mc0.z ? (__bf16)S0[2] : (__bf16)0.0f;                                \
        pa[3] = mc0.w ? (__bf16)S0[3] : (__bf16)0.0f;                                \
        pa[4] = mc1.x ? (__bf16)S1[0] : (__bf16)0.0f;                                \
        pa[5] = mc1.y ? (__bf16)S1[1] : (__bf16)0.0f;                                \
        pa[6] = mc1.z ? (__bf16)S1[2] : (__bf16)0.0f;                                \
        pa[7] = mc1.w ? (__bf16)S1[3] : (__bf16)0.0f;                                \
        __builtin_amdgcn_s_setprio(1);                                               \
        _Pragma("unroll")                                                            \
        for (int dt = 0; dt < 8; ++dt) {                                             \
            const __bf16* vrow = &vtb[(16*dt + ln)*VT_PITCH];                        \
            bf16x4 va = *(const bf16x4*)&vrow[vlo];                                  \
            bf16x4 vb = *(const bf16x4*)&vrow[vhi];                                  \
            bf16x8 vf = { va[0], va[1], va[2], va[3], vb[0], vb[1], vb[2], vb[3] };  \
            Oacc[dt] = MFMA16(pa, vf, Oacc[dt]);                                     \
        }                                                                            \
        __builtin_amdgcn_s_setprio(0);                                               \
    }

    for (int it = 0; it < NITER; it += 2) {
        STEP(it,     0, mA0, mA1, mB0, mB1);
        STEP(it + 1, 1, mB0, mB1, mA0, mA1);
    }
#undef STEP

    // ---- epilogue: folded scale 2*sqrt(D), store fp32
    const float SCALE = 22.62741699796952f;  // 2 * sqrt(128)
    #pragma unroll
    for (int dt = 0; dt < 8; ++dt) {
        #pragma unroll
        for (int r = 0; r < 4; ++r)
            optr[(size_t)(row0 + r)*D_ + 16*dt + ln] = Oacc[dt][r] * SCALE;
    }
}

extern "C" void kernel_launch(void* const* d_in, const int* in_sizes, int n_in,
                              void* d_out, int out_size, void* d_ws, size_t ws_size,
                              hipStream_t stream) {
    (void)in_sizes; (void)n_in; (void)d_ws; (void)ws_size; (void)out_size;
    const float* Q = (const float*)d_in[0];
    const float* K = (const float*)d_in[1];
    const float* V = (const float*)d_in[2];
    const int*   M = (const int*)d_in[3];
    float* Out = (float*)d_out;

    dim3 grid(B_ * H_ * (SQ_ / QT));   // 512 blocks
    attn_drop_kernel<<<grid, 512, 0, stream>>>(Q, K, V, M, Out);
}